// Round 2
// baseline (282.177 us; speedup 1.0000x reference)
//
#include <hip/hip_runtime.h>
#include <hip/hip_bf16.h>

// Problem constants (fixed by setup_inputs)
#define N_NODES   100000
#define MAX_DEG   64
#define NODE_DIM  256
#define NUM_V     8192
#define NSAMP     16
#define GROUP_DIM 4
#define SENTINEL  (N_NODES - 1)

// ---------------- Fused kernel: mat-vec (l = f[id] @ W + b) + sampler ------
// R2: one block per v (8192 blocks, 256 threads), replacing the separate
// 64x64-tile GEMM + 8 MB l round-trip + second dispatch.
//
// Rationale (counters R0/R1): the gather phase is pinned at ~3 TB/s on the
// L2-miss path across every concurrency arrangement tried (per-CU miss-slot
// limit; static BW ceilings are all far away). The mat-vec phase uses VALU +
// L2-HIT bandwidth (W is 256 KB, resident in every XCD's L2), which the
// miss-bound gather leaves idle -> across ~3 resident blocks/CU the mat-vec
// hides under other blocks' gather misses.
//
// Numerics: acc=0; k sequential 0..255; bias added after the sum — identical
// summation order to the old gemm kernel (k0-tiles were sequential too), so
// l is bit-identical and the verbatim R0 gather/argmin produces bit-identical
// outputs.
__global__ __launch_bounds__(256) void fused_sampler_kernel(
    const int* __restrict__ ids,
    const int* __restrict__ adj,
    const float* __restrict__ features,
    const float* __restrict__ W,
    const float* __restrict__ bias,
    float* __restrict__ out_sel,
    float* __restrict__ out_att,
    float* __restrict__ out_nz1,
    float* __restrict__ out_nz2) {
  __shared__ float f_s[NODE_DIM];
  __shared__ float l_s[NODE_DIM];
  __shared__ int   adj_s[MAX_DEG];
  __shared__ float nz_s[NSAMP];

  const int v   = blockIdx.x;
  const int tid = threadIdx.x;
  const int nid = ids[v];

  // Stage own feature row (coalesced 1 KB) and adj row up front.
  f_s[tid] = features[(size_t)nid * NODE_DIM + tid];
  if (tid < MAX_DEG) adj_s[tid] = adj[(size_t)nid * MAX_DEG + tid];
  __syncthreads();

  // ---- mat-vec: l_s[tid] = sum_k f_s[k] * W[k][tid]  (+ bias after) ----
  // W[k][tid]: for fixed k, threads read a contiguous 1 KB row -> coalesced,
  // L2-hit. f_s[k] is a wave-uniform LDS broadcast. Serial fp32 chain keeps
  // the summation order bit-identical to the old gemm.
  {
    float acc = 0.0f;
#pragma unroll 8
    for (int k = 0; k < NODE_DIM; ++k) {
      acc += f_s[k] * W[(size_t)k * NODE_DIM + tid];
    }
    l_s[tid] = acc + bias[tid];
  }
  __syncthreads();

  // ---- gather + grouped argmin: verbatim from the verified R0 kernel ----
  const int wave = tid >> 6;       // 0..3
  const int lane = tid & 63;
  const int q    = lane >> 2;      // 0..15: neighbor slot within wave
  const int sub  = lane & 3;       // 0..3 : dim-chunk within quad
  const int k    = wave * 16 + q;  // neighbor index 0..63

  const int nb = adj_s[k];
  const float* __restrict__ rowp = features + (size_t)nb * NODE_DIM + sub * 4;
  const float* __restrict__ lp   = l_s + sub * 4;

  float p = 0.0f;
#pragma unroll
  for (int c = 0; c < 16; ++c) {
    const float4 f  = *reinterpret_cast<const float4*>(rowp + c * 16);
    const float4 lv = *reinterpret_cast<const float4*>(lp + c * 16);
    p += f.x * lv.x + f.y * lv.y + f.z * lv.z + f.w * lv.w;
  }
  p += __shfl_xor(p, 1, 64);
  p += __shfl_xor(p, 2, 64);
  float s = p > 0.0f ? p : 0.0f;   // relu

  int g = q & 3;
  {
    float os = __shfl_xor(s, 4, 64);
    int   og = __shfl_xor(g, 4, 64);
    if (os < s || (os == s && og < g)) { s = os; g = og; }
    os = __shfl_xor(s, 8, 64);
    og = __shfl_xor(g, 8, 64);
    if (os < s || (os == s && og < g)) { s = os; g = og; }
  }

  if ((lane & 15) == 0) {
    const int gl    = lane >> 4;
    const int s_idx = wave * 4 + gl;
    const int selid = adj_s[s_idx * GROUP_DIM + g];
    out_sel[(size_t)v * NSAMP + s_idx] = (float)selid;
    out_att[(size_t)v * NSAMP + s_idx] = 1.0f;
    nz_s[s_idx] = (selid == SENTINEL) ? 0.0f : 1.0f;
  }
  __syncthreads();

  if (tid == 0) {
    float nz = 0.0f;
#pragma unroll
    for (int t = 0; t < NSAMP; ++t) nz += nz_s[t];
    out_nz1[v] = nz;
    out_nz2[v] = nz;
  }
}

extern "C" void kernel_launch(void* const* d_in, const int* in_sizes, int n_in,
                              void* d_out, int out_size, void* d_ws,
                              size_t ws_size, hipStream_t stream) {
  const int*   ids      = (const int*)d_in[0];
  const int*   adj      = (const int*)d_in[1];
  const float* features = (const float*)d_in[2];
  const float* W        = (const float*)d_in[3];
  const float* bias     = (const float*)d_in[4];

  float* out     = (float*)d_out;
  float* out_sel = out;
  float* out_att = out + (size_t)NUM_V * NSAMP;
  float* out_nz1 = out + (size_t)2 * NUM_V * NSAMP;
  float* out_nz2 = out_nz1 + NUM_V;

  fused_sampler_kernel<<<NUM_V, 256, 0, stream>>>(
      ids, adj, features, W, bias, out_sel, out_att, out_nz1, out_nz2);
}

// Round 4
// 235.395 us; speedup vs baseline: 1.1987x; 1.1987x over previous
//
#include <hip/hip_runtime.h>
#include <hip/hip_bf16.h>

// Problem constants (fixed by setup_inputs)
#define N_NODES   100000
#define MAX_DEG   64
#define NODE_DIM  256
#define NUM_V     8192
#define NSAMP     16
#define GROUP_DIM 4
#define SENTINEL  (N_NODES - 1)

// ---------------- Fused kernel, R4 (= R3 resubmit; infra flake) ------------
// R2 failure analysis: per-block W sweep (256 KB) x 8192 blocks = 2 GB L2
// traffic (~58 us) that serialized against the gather (gather BW 3.08 ->
// 1.73 TB/s). Fix: amortize W over 8 v's per block -> 256 MB L2 (~8 us,
// hides under the miss-bound gather). Keeps fusion's wins: no gemm dispatch,
// no 16 MB l round-trip, one launch.
//
// Numerics: mat-vec k-sum sequential 0..255 (fma), bias added after -> same
// bits as R2's mat-vec (passed absmax 0.0). Gather/argmin verbatim R0.
#define VPB 8

__global__ __launch_bounds__(256) void fused_sampler_kernel(
    const int* __restrict__ ids,
    const int* __restrict__ adj,
    const float* __restrict__ features,
    const float* __restrict__ W,
    const float* __restrict__ bias,
    float* __restrict__ out_sel,
    float* __restrict__ out_att,
    float* __restrict__ out_nz1,
    float* __restrict__ out_nz2) {
  __shared__ float f_s[VPB][NODE_DIM];
  __shared__ float l_s[VPB][NODE_DIM];
  __shared__ int   adj_s[VPB][MAX_DEG];
  __shared__ float nz_s[VPB][NSAMP];
  __shared__ int   nid_s[VPB];

  const int tid = threadIdx.x;
  const int v0  = blockIdx.x * VPB;

  if (tid < VPB) nid_s[tid] = ids[v0 + tid];
  __syncthreads();

  // Stage own-node feature rows: 8 x 256 floats as 512 float4s (coalesced).
  {
    const int i0 = tid;          // float4 index 0..255
    const int i1 = tid + 256;    // float4 index 256..511
    const int vi0 = i0 >> 6, d0 = (i0 & 63) * 4;
    const int vi1 = i1 >> 6, d1 = (i1 & 63) * 4;
    *reinterpret_cast<float4*>(&f_s[vi0][d0]) =
        *reinterpret_cast<const float4*>(
            &features[(size_t)nid_s[vi0] * NODE_DIM + d0]);
    *reinterpret_cast<float4*>(&f_s[vi1][d1]) =
        *reinterpret_cast<const float4*>(
            &features[(size_t)nid_s[vi1] * NODE_DIM + d1]);
  }
  // Stage adj rows: 8 x 64 ints, 2 per thread (coalesced within rows).
  {
    const int i0 = tid, i1 = tid + 256;
    adj_s[i0 >> 6][i0 & 63] =
        adj[(size_t)nid_s[i0 >> 6] * MAX_DEG + (i0 & 63)];
    adj_s[i1 >> 6][i1 & 63] =
        adj[(size_t)nid_s[i1 >> 6] * MAX_DEG + (i1 & 63)];
  }
  __syncthreads();

  // ---- mat-vec: l_s[vi][tid] = sum_k f_s[vi][k] * W[k][tid] + bias[tid] ----
  // Thread owns output column d = tid for all 8 vi. W row reads are
  // full-wave coalesced 1 KB, L2-resident per XCD (W = 256 KB).
  // Summation order per acc: k = 0..255 sequential (bit-identical to R2).
  {
    float acc[VPB] = {};
#pragma unroll 2
    for (int k4 = 0; k4 < NODE_DIM; k4 += 4) {
      const float w0 = W[(size_t)(k4 + 0) * NODE_DIM + tid];
      const float w1 = W[(size_t)(k4 + 1) * NODE_DIM + tid];
      const float w2 = W[(size_t)(k4 + 2) * NODE_DIM + tid];
      const float w3 = W[(size_t)(k4 + 3) * NODE_DIM + tid];
#pragma unroll
      for (int vi = 0; vi < VPB; ++vi) {
        const float4 f = *reinterpret_cast<const float4*>(&f_s[vi][k4]);
        acc[vi] += f.x * w0;
        acc[vi] += f.y * w1;
        acc[vi] += f.z * w2;
        acc[vi] += f.w * w3;
      }
    }
    const float bv = bias[tid];
#pragma unroll
    for (int vi = 0; vi < VPB; ++vi) l_s[vi][tid] = acc[vi] + bv;
  }
  __syncthreads();

  // ---- gather + grouped argmin: R0 quad pattern, serial over vi ----
  const int wave = tid >> 6;       // 0..3
  const int lane = tid & 63;
  const int q    = lane >> 2;      // 0..15: neighbor slot within wave
  const int sub  = lane & 3;       // 0..3 : dim-chunk within quad
  const int kslot = wave * 16 + q; // neighbor index 0..63

  // unroll 1: keep per-vi 16-deep MLP without cross-vi register blow-up
  // (R1 lesson: 200 VGPR -> 10% occupancy).
#pragma unroll 1
  for (int vi = 0; vi < VPB; ++vi) {
    const int nb = adj_s[vi][kslot];
    const float* __restrict__ rowp =
        features + (size_t)nb * NODE_DIM + sub * 4;
    const float* __restrict__ lp = &l_s[vi][sub * 4];

    float p = 0.0f;
#pragma unroll
    for (int c = 0; c < 16; ++c) {
      const float4 f  = *reinterpret_cast<const float4*>(rowp + c * 16);
      const float4 lv = *reinterpret_cast<const float4*>(lp + c * 16);
      p += f.x * lv.x + f.y * lv.y + f.z * lv.z + f.w * lv.w;
    }
    p += __shfl_xor(p, 1, 64);
    p += __shfl_xor(p, 2, 64);
    float s = p > 0.0f ? p : 0.0f;   // relu

    int g = q & 3;
    {
      float os = __shfl_xor(s, 4, 64);
      int   og = __shfl_xor(g, 4, 64);
      if (os < s || (os == s && og < g)) { s = os; g = og; }
      os = __shfl_xor(s, 8, 64);
      og = __shfl_xor(g, 8, 64);
      if (os < s || (os == s && og < g)) { s = os; g = og; }
    }

    if ((lane & 15) == 0) {
      const int gl    = lane >> 4;
      const int s_idx = wave * 4 + gl;
      const int selid = adj_s[vi][s_idx * GROUP_DIM + g];
      const int vv    = v0 + vi;
      out_sel[(size_t)vv * NSAMP + s_idx] = (float)selid;
      out_att[(size_t)vv * NSAMP + s_idx] = 1.0f;
      nz_s[vi][s_idx] = (selid == SENTINEL) ? 0.0f : 1.0f;
    }
  }
  __syncthreads();

  if (tid < VPB) {
    float nz = 0.0f;
#pragma unroll
    for (int t = 0; t < NSAMP; ++t) nz += nz_s[tid][t];
    out_nz1[v0 + tid] = nz;
    out_nz2[v0 + tid] = nz;
  }
}

extern "C" void kernel_launch(void* const* d_in, const int* in_sizes, int n_in,
                              void* d_out, int out_size, void* d_ws,
                              size_t ws_size, hipStream_t stream) {
  const int*   ids      = (const int*)d_in[0];
  const int*   adj      = (const int*)d_in[1];
  const float* features = (const float*)d_in[2];
  const float* W        = (const float*)d_in[3];
  const float* bias     = (const float*)d_in[4];

  float* out     = (float*)d_out;
  float* out_sel = out;
  float* out_att = out + (size_t)NUM_V * NSAMP;
  float* out_nz1 = out + (size_t)2 * NUM_V * NSAMP;
  float* out_nz2 = out_nz1 + NUM_V;

  fused_sampler_kernel<<<NUM_V / VPB, 256, 0, stream>>>(
      ids, adj, features, W, bias, out_sel, out_att, out_nz1, out_nz2);
}